// Round 2
// baseline (3010.461 us; speedup 1.0000x reference)
//
#include <hip/hip_runtime.h>

// GlobalFilter (GFNet): out = irfft2(rfft2(x)·W, ortho) == per-channel 16x16
// circular convolution with k[:,:,c] = inverse transform of W. ortho norms cancel.
//
// Lessons:
//  R1: k from global -> exposed L2 latency (k reads are a per-lane gather; k
//      MUST stay in LDS).
//  R2: lane-varying LDS x-column -> bank conflicts; dynamic reg-array index
//      -> scratch. NEVER index a register array with a runtime value.
//  R3: conditionals in hot unrolled loops -> spill. Keep the loop body
//      conditional-free (redundant qq=15 prefetch instead of an if).
//  R4 (300 us): both full tiles in LDS = 64 KB -> 2 blocks/CU -> 1 wave/SIMD.
//      VALUBusy 50%: every per-qq kv[16] LDS burst is an unhidden stall.
//  R5 (281 us): x column j=(-qq)&15 consumed exactly once -> stream it as a
//      2 KB double-buffered column via global_load_lds (lane-linear dest).
//      LDS 40960 B, 2 batches/block sharing ks. Occupancy 10.7->27%,
//      VALUBusy 50->66%, conv 185->149 us. Theory confirmed: occupancy-bound.
//  R6 (this version): 4*40960 = 163840 = exactly the 160 KiB LDS pool, and
//      VGPR 84 < 128. Only __launch_bounds__(256,3) was holding occupancy at
//      3 blocks/CU. Bump to (256,4): 16 waves/CU, 4 waves/SIMD. Per-SIMD VALU
//      demand (4x2048 cyc/qq) still exceeds per-CU LDS demand (~6144 cyc/qq),
//      so the 4th wave converts stall time into FMA issue.

constexpr int PP = 16;   // patch size
constexpr int NS = 256;  // PP*PP spatial
constexpr int CH = 768;  // channels
constexpr int NB = 128;  // batch

// async global->LDS, 16B per lane. lds ptr must be wave-uniform base; HW adds
// lane*16. Source address is per-lane.
__device__ __forceinline__ void cp_g2s_16(const void* g, void* s) {
    __builtin_amdgcn_global_load_lds(
        (const __attribute__((address_space(1))) void*)g,
        (__attribute__((address_space(3))) void*)s, 16, 0, 0);
}

// ---------------- Kernel A: build real conv kernel k[p*16+q][c] -------------
__global__ void gf_build_k(const float* __restrict__ w, float* __restrict__ kbuf) {
    __shared__ float ct[16], st[16];
    if (threadIdx.x < 16) {
        const float ang = 6.28318530717958647692f * (float)threadIdx.x * (1.0f / 16.0f);
        ct[threadIdx.x] = cosf(ang);
        st[threadIdx.x] = sinf(ang);
    }
    __syncthreads();

    const int pq = blockIdx.x;                              // 0..255
    const int c  = blockIdx.y * blockDim.x + threadIdx.x;   // 0..767
    const int p = pq >> 4, q = pq & 15;

    float acc = 0.0f;
#pragma unroll 1
    for (int u = 0; u < 16; ++u) {
        const float* wu = w + (size_t)(u * 9) * 2 * CH + 2 * c;
#pragma unroll
        for (int v = 0; v < 9; ++v) {
            const float cv = (v == 0 || v == 8) ? 1.0f : 2.0f;
            const int t = (u * p + v * q) & 15;  // lane-uniform -> LDS broadcast
            const float wr = wu[(size_t)v * 2 * CH];
            const float wi = wu[(size_t)v * 2 * CH + 1];
            acc += cv * (wr * ct[t] - wi * st[t]);
        }
    }
    kbuf[pq * CH + c] = acc * (1.0f / 256.0f);
}

// ---------------- Kernel B: depthwise 16x16 circular conv -------------------
// block = 256 threads = 2 batches x (8 ch-groups x 16 n-cols). 40 KB LDS:
//   ks[256][32]          32 KB  (shared by both batch halves)
//   xcol[2][2][16][32]    8 KB  (double-buffered x column per batch half)
// 4 blocks/CU (160 KB exactly) -> 16 waves/CU (4/SIMD).
__global__ __launch_bounds__(256, 4) void gf_conv(const float* __restrict__ x,
                                                  const float* __restrict__ kbuf,
                                                  float* __restrict__ out) {
    __shared__ __align__(16) float ks[NS][32];
    __shared__ __align__(16) float xcol[2][2][16][32];  // [buf][half][d][ch]

    const int tid  = threadIdx.x;
    const int half = tid >> 7;                 // batch half 0/1
    const int b    = (blockIdx.y << 1) | half;
    const int c0   = blockIdx.x * 32;
    const int wave = tid >> 6;                 // 0..3 (wave-uniform)
    const int idx  = tid & 127;                // id within batch half
    const int dr   = idx >> 3;                 // stage row 0..15
    const int ch4  = (idx & 7) << 2;           // stage chan offset (floats)

    const float* xb = x + (size_t)b * NS * CH + c0;

    // ---- stage k tile: 8 x global_load_lds per thread, lane-linear dest.
    // wave w, instr i covers ks bytes [i*4096 + w*1024, +1024):
    //   s = i*32 + (tid>>3), ch = (tid&7)*4  (matches lds flat offset)
    {
        const int srow = tid >> 3;             // 0..31
        const int kch4 = (tid & 7) << 2;
        const float* kb = kbuf + c0;
        float* lbase = &ks[0][0] + wave * 256; // 1 KB per wave, uniform
#pragma unroll
        for (int i = 0; i < 8; ++i)
            cp_g2s_16(kb + (size_t)(i * 32 + srow) * CH + kch4, lbase + i * 1024);
    }
    // ---- stage x column j(0)=0 into buf 0
    {
        float* lbase = &xcol[0][half][0][0] + (wave & 1) * 256;  // uniform
        cp_g2s_16(xb + (size_t)(dr * 16 + 0) * CH + ch4, lbase);
    }
    __syncthreads();  // drains vmcnt(0): all staging landed

    const int chq = (tid & 7) << 2;   // channel float4 within tile
    const int n   = (tid >> 3) & 15;  // output column 0..15

    float4 acc[16];
#pragma unroll
    for (int m = 0; m < 16; ++m) acc[m] = make_float4(0.f, 0.f, 0.f, 0.f);

#pragma unroll 1
    for (int qq = 0; qq < 16; ++qq) {
        // prefetch next column j(qq+1) = (15-qq)&15 into buf[(qq+1)&1].
        // (qq=15: redundant reload of col 0 -> branch-free loop body, R3)
        {
            float* lbase = &xcol[(qq + 1) & 1][half][0][0] + (wave & 1) * 256;
            cp_g2s_16(xb + (size_t)(dr * 16 + ((15 - qq) & 15)) * CH + ch4, lbase);
        }

        const int q = (qq + n) & 15;  // lane-varying k column
        const float4* xrow = (const float4*)&xcol[qq & 1][half][0][chq];

        // kv[16]: distinct-address b128 LDS reads (conflict-free, measured 0)
        float4 kv[16];
#pragma unroll
        for (int p = 0; p < 16; ++p)
            kv[p] = *(const float4*)&ks[(p << 4) | q][chq];

        // d = (m - p) & 15: one broadcast x row per d, all indices static
#pragma unroll
        for (int d = 0; d < 16; ++d) {
            const float4 xx = xrow[d * 8];  // row stride = 32 floats = 8 float4
#pragma unroll
            for (int p = 0; p < 16; ++p) {
                const int m = (p + d) & 15;  // compile-time
                acc[m].x = fmaf(kv[p].x, xx.x, acc[m].x);
                acc[m].y = fmaf(kv[p].y, xx.y, acc[m].y);
                acc[m].z = fmaf(kv[p].z, xx.z, acc[m].z);
                acc[m].w = fmaf(kv[p].w, xx.w, acc[m].w);
            }
        }
        // drains the prefetch (vmcnt) and orders buffer reuse across waves
        __syncthreads();
    }

    float* ob = out + (size_t)b * NS * CH + c0 + chq;
#pragma unroll
    for (int m = 0; m < 16; ++m)
        *(float4*)(ob + (size_t)((m << 4) + n) * CH) = acc[m];
}

// ---------------------------------------------------------------------------
extern "C" void kernel_launch(void* const* d_in, const int* in_sizes, int n_in,
                              void* d_out, int out_size, void* d_ws, size_t ws_size,
                              hipStream_t stream) {
    const float* x = (const float*)d_in[0];        // [128, 256, 768] fp32
    const float* w = (const float*)d_in[1];        // [16, 9, 768, 2] fp32
    float* out  = (float*)d_out;                   // [128, 256, 768] fp32
    float* kbuf = (float*)d_ws;                    // 256*768 fp32 = 768 KB

    gf_build_k<<<dim3(256, 3), 256, 0, stream>>>(w, kbuf);
    gf_conv<<<dim3(CH / 32, NB / 2), 256, 0, stream>>>(x, kbuf, out);
}

// Round 3
// 2756.924 us; speedup vs baseline: 1.0920x; 1.0920x over previous
//
#include <hip/hip_runtime.h>

// GlobalFilter (GFNet): out = irfft2(rfft2(x)·W, ortho) == per-channel 16x16
// circular convolution with k[:,:,c] = inverse transform of W. ortho norms cancel.
//
// Lessons:
//  R1: k from global -> exposed L2 latency (k reads are a per-lane GATHER; k
//      MUST stay in LDS). x rows are NOT a gather (see R7) - different rule.
//  R2: lane-varying LDS x-column -> bank conflicts; dynamic reg-array index
//      -> scratch. NEVER index a register array with a runtime value.
//  R3: conditionals in hot unrolled loops -> spill. Spill signature in
//      counters: WRITE_SIZE >> output bytes, FETCH >> input bytes.
//  R4 (300 us): both full tiles in LDS = 64 KB -> 2 blocks/CU -> 1 wave/SIMD.
//      VALUBusy 50%: every per-qq kv[16] LDS burst is an unhidden stall.
//  R5 (281 us): stream x column via global_load_lds double-buffer; LDS 40 KB,
//      2 batches/block. Occupancy 10.7->27%, VALUBusy 50->66%, conv 185->149us.
//  R6 (3010 us!): __launch_bounds__(256,4) with 40 KB LDS: 4 blocks/CU does
//      NOT actually fit (R5 measured ~3) -> allocator degenerated to 64 VGPR
//      + full acc/kv spill (WRITE 8.8 GB). NEVER force a min-occupancy the
//      LDS footprint can't satisfy.
//  R7 (this version): the x column read xrow[d] is n-independent -> all 8
//      lane-groups of a wave read the SAME 128 B row slice. That coalesces
//      perfectly as a GLOBAL load (1-2 cachelines/instr) - x never needs LDS.
//      Drop xcol entirely: LDS = 32 KB ks only -> 4+ blocks/CU; ZERO in-loop
//      barriers (waves fully decoupled); no prefetch machinery. x is read 2x
//      (both waves of a half), +56 MB HBM = ~9 us, dwarfed by the VALU win.

constexpr int PP = 16;   // patch size
constexpr int NS = 256;  // PP*PP spatial
constexpr int CH = 768;  // channels
constexpr int NB = 128;  // batch

// async global->LDS, 16B per lane. lds ptr must be wave-uniform base; HW adds
// lane*16. Source address is per-lane.
__device__ __forceinline__ void cp_g2s_16(const void* g, void* s) {
    __builtin_amdgcn_global_load_lds(
        (const __attribute__((address_space(1))) void*)g,
        (__attribute__((address_space(3))) void*)s, 16, 0, 0);
}

// ---------------- Kernel A: build real conv kernel k[p*16+q][c] -------------
__global__ void gf_build_k(const float* __restrict__ w, float* __restrict__ kbuf) {
    __shared__ float ct[16], st[16];
    if (threadIdx.x < 16) {
        const float ang = 6.28318530717958647692f * (float)threadIdx.x * (1.0f / 16.0f);
        ct[threadIdx.x] = cosf(ang);
        st[threadIdx.x] = sinf(ang);
    }
    __syncthreads();

    const int pq = blockIdx.x;                              // 0..255
    const int c  = blockIdx.y * blockDim.x + threadIdx.x;   // 0..767
    const int p = pq >> 4, q = pq & 15;

    float acc = 0.0f;
#pragma unroll 1
    for (int u = 0; u < 16; ++u) {
        const float* wu = w + (size_t)(u * 9) * 2 * CH + 2 * c;
#pragma unroll
        for (int v = 0; v < 9; ++v) {
            const float cv = (v == 0 || v == 8) ? 1.0f : 2.0f;
            const int t = (u * p + v * q) & 15;  // lane-uniform -> LDS broadcast
            const float wr = wu[(size_t)v * 2 * CH];
            const float wi = wu[(size_t)v * 2 * CH + 1];
            acc += cv * (wr * ct[t] - wi * st[t]);
        }
    }
    kbuf[pq * CH + c] = acc * (1.0f / 256.0f);
}

// ---------------- Kernel B: depthwise 16x16 circular conv -------------------
// block = 256 threads = 2 batches x (8 ch-groups x 16 n-cols). 32 KB LDS:
//   ks[256][32]  (shared by both batch halves; k is a per-lane gather -> LDS)
// x read directly from global (n-independent rows, perfectly coalesced).
// No in-loop barriers: waves fully decoupled after the ks-staging barrier.
__global__ __launch_bounds__(256, 4) void gf_conv(const float* __restrict__ x,
                                                  const float* __restrict__ kbuf,
                                                  float* __restrict__ out) {
    __shared__ __align__(16) float ks[NS][32];

    const int tid  = threadIdx.x;
    const int half = tid >> 7;                 // batch half 0/1
    const int b    = (blockIdx.y << 1) | half;
    const int c0   = blockIdx.x * 32;
    const int wave = tid >> 6;                 // 0..3 (wave-uniform)

    // ---- stage k tile: 8 x global_load_lds per thread, lane-linear dest.
    // wave w, instr i covers ks bytes [i*4096 + w*1024, +1024):
    //   s = i*32 + (tid>>3), ch = (tid&7)*4  (matches lds flat offset)
    {
        const int srow = tid >> 3;             // 0..31
        const int kch4 = (tid & 7) << 2;
        const float* kb = kbuf + c0;
        float* lbase = &ks[0][0] + wave * 256; // 1 KB per wave, uniform
#pragma unroll
        for (int i = 0; i < 8; ++i)
            cp_g2s_16(kb + (size_t)(i * 32 + srow) * CH + kch4, lbase + i * 1024);
    }
    __syncthreads();  // drains vmcnt(0): ks staged. Last barrier in the kernel.

    const int chq = (tid & 7) << 2;   // channel float4 within tile
    const int n   = (tid >> 3) & 15;  // output column 0..15
    const float* xb = x + (size_t)b * NS * CH + c0 + chq;

    float4 acc[16];
#pragma unroll
    for (int m = 0; m < 16; ++m) acc[m] = make_float4(0.f, 0.f, 0.f, 0.f);

#pragma unroll 1
    for (int qq = 0; qq < 16; ++qq) {
        const int j = (16 - qq) & 15;  // lane-UNIFORM x column
        const int q = (qq + n) & 15;   // lane-varying k column
        const float* xcol = xb + (size_t)j * CH;  // rows s = d*16 + j

        // kv[16]: distinct-address b128 LDS reads (conflict-free, measured 0)
        float4 kv[16];
#pragma unroll
        for (int p = 0; p < 16; ++p)
            kv[p] = *(const float4*)&ks[(p << 4) | q][chq];

        // d = (m - p) & 15: one coalesced global x row per d, indices static
#pragma unroll
        for (int d = 0; d < 16; ++d) {
            const float4 xx = *(const float4*)(xcol + (size_t)(d << 4) * CH);
#pragma unroll
            for (int p = 0; p < 16; ++p) {
                const int m = (p + d) & 15;  // compile-time
                acc[m].x = fmaf(kv[p].x, xx.x, acc[m].x);
                acc[m].y = fmaf(kv[p].y, xx.y, acc[m].y);
                acc[m].z = fmaf(kv[p].z, xx.z, acc[m].z);
                acc[m].w = fmaf(kv[p].w, xx.w, acc[m].w);
            }
        }
    }

    float* ob = out + (size_t)b * NS * CH + c0 + chq;
#pragma unroll
    for (int m = 0; m < 16; ++m)
        *(float4*)(ob + (size_t)((m << 4) + n) * CH) = acc[m];
}

// ---------------------------------------------------------------------------
extern "C" void kernel_launch(void* const* d_in, const int* in_sizes, int n_in,
                              void* d_out, int out_size, void* d_ws, size_t ws_size,
                              hipStream_t stream) {
    const float* x = (const float*)d_in[0];        // [128, 256, 768] fp32
    const float* w = (const float*)d_in[1];        // [16, 9, 768, 2] fp32
    float* out  = (float*)d_out;                   // [128, 256, 768] fp32
    float* kbuf = (float*)d_ws;                    // 256*768 fp32 = 768 KB

    gf_build_k<<<dim3(256, 3), 256, 0, stream>>>(w, kbuf);
    gf_conv<<<dim3(CH / 32, NB / 2), 256, 0, stream>>>(x, kbuf, out);
}

// Round 4
// 424.585 us; speedup vs baseline: 7.0904x; 6.4932x over previous
//
#include <hip/hip_runtime.h>

// GlobalFilter (GFNet): out = irfft2(rfft2(x)·W, ortho) == per-channel 16x16
// circular convolution with k[:,:,c] = inverse transform of W. ortho norms cancel.
//
// Lessons:
//  R1: k from global -> exposed L2 latency (k reads are a per-lane GATHER; k
//      MUST stay in LDS). x rows are NOT a gather (see R7) - different rule.
//  R2: lane-varying LDS x-column -> bank conflicts; dynamic reg-array index
//      -> scratch. NEVER index a register array with a runtime value.
//  R3: conditionals in hot unrolled loops -> spill. Spill signature in
//      counters: WRITE_SIZE >> output bytes, FETCH >> input bytes, VGPR=64.
//  R4 (300 us): both full tiles in LDS = 64 KB -> 2 blocks/CU -> 1 wave/SIMD.
//      VALUBusy 50%: every per-qq kv[16] LDS burst is an unhidden stall.
//  R5 (281 us): stream x column via global_load_lds double-buffer; LDS 40 KB,
//      2 batches/block. Occupancy 10.7->27%, VALUBusy 50->66%, conv 185->149us.
//  R6/R7 (3010/2757 us!): __launch_bounds__(256,4) caps the UNIFIED reg file
//      at 512/4 = 128/thread. Live set acc[16](64) + kv[16](64) + addr ~= 140
//      CANNOT fit -> allocator degenerates to 64 VGPR + scratch (WRITE 6-9 GB).
//      R7 proved LDS was never the limiter (32 KB, still spilled). LESSON:
//      this register tile supports AT MOST 3 waves/SIMD; never declare 4.
//  R8 (this version): keep R7's structure (x direct from global - coalesced,
//      n-independent rows; LDS = 32 KB ks only; ZERO in-loop barriers) at
//      __launch_bounds__(256,3). Same 27% occupancy as R5 but waves are fully
//      decoupled: no 16x per-qq barrier drains, loads pipeline across d/qq.

constexpr int PP = 16;   // patch size
constexpr int NS = 256;  // PP*PP spatial
constexpr int CH = 768;  // channels
constexpr int NB = 128;  // batch

// async global->LDS, 16B per lane. lds ptr must be wave-uniform base; HW adds
// lane*16. Source address is per-lane.
__device__ __forceinline__ void cp_g2s_16(const void* g, void* s) {
    __builtin_amdgcn_global_load_lds(
        (const __attribute__((address_space(1))) void*)g,
        (__attribute__((address_space(3))) void*)s, 16, 0, 0);
}

// ---------------- Kernel A: build real conv kernel k[p*16+q][c] -------------
__global__ void gf_build_k(const float* __restrict__ w, float* __restrict__ kbuf) {
    __shared__ float ct[16], st[16];
    if (threadIdx.x < 16) {
        const float ang = 6.28318530717958647692f * (float)threadIdx.x * (1.0f / 16.0f);
        ct[threadIdx.x] = cosf(ang);
        st[threadIdx.x] = sinf(ang);
    }
    __syncthreads();

    const int pq = blockIdx.x;                              // 0..255
    const int c  = blockIdx.y * blockDim.x + threadIdx.x;   // 0..767
    const int p = pq >> 4, q = pq & 15;

    float acc = 0.0f;
#pragma unroll 1
    for (int u = 0; u < 16; ++u) {
        const float* wu = w + (size_t)(u * 9) * 2 * CH + 2 * c;
#pragma unroll
        for (int v = 0; v < 9; ++v) {
            const float cv = (v == 0 || v == 8) ? 1.0f : 2.0f;
            const int t = (u * p + v * q) & 15;  // lane-uniform -> LDS broadcast
            const float wr = wu[(size_t)v * 2 * CH];
            const float wi = wu[(size_t)v * 2 * CH + 1];
            acc += cv * (wr * ct[t] - wi * st[t]);
        }
    }
    kbuf[pq * CH + c] = acc * (1.0f / 256.0f);
}

// ---------------- Kernel B: depthwise 16x16 circular conv -------------------
// block = 256 threads = 2 batches x (8 ch-groups x 16 n-cols). 32 KB LDS:
//   ks[256][32]  (shared by both batch halves; k is a per-lane gather -> LDS)
// x read directly from global (n-independent rows, perfectly coalesced).
// No in-loop barriers: waves fully decoupled after the ks-staging barrier.
__global__ __launch_bounds__(256, 3) void gf_conv(const float* __restrict__ x,
                                                  const float* __restrict__ kbuf,
                                                  float* __restrict__ out) {
    __shared__ __align__(16) float ks[NS][32];

    const int tid  = threadIdx.x;
    const int half = tid >> 7;                 // batch half 0/1
    const int b    = (blockIdx.y << 1) | half;
    const int c0   = blockIdx.x * 32;
    const int wave = tid >> 6;                 // 0..3 (wave-uniform)

    // ---- stage k tile: 8 x global_load_lds per thread, lane-linear dest.
    // wave w, instr i covers ks bytes [i*4096 + w*1024, +1024):
    //   s = i*32 + (tid>>3), ch = (tid&7)*4  (matches lds flat offset)
    {
        const int srow = tid >> 3;             // 0..31
        const int kch4 = (tid & 7) << 2;
        const float* kb = kbuf + c0;
        float* lbase = &ks[0][0] + wave * 256; // 1 KB per wave, uniform
#pragma unroll
        for (int i = 0; i < 8; ++i)
            cp_g2s_16(kb + (size_t)(i * 32 + srow) * CH + kch4, lbase + i * 1024);
    }
    __syncthreads();  // drains vmcnt(0): ks staged. Last barrier in the kernel.

    const int chq = (tid & 7) << 2;   // channel float4 within tile
    const int n   = (tid >> 3) & 15;  // output column 0..15
    const float* xb = x + (size_t)b * NS * CH + c0 + chq;

    float4 acc[16];
#pragma unroll
    for (int m = 0; m < 16; ++m) acc[m] = make_float4(0.f, 0.f, 0.f, 0.f);

#pragma unroll 1
    for (int qq = 0; qq < 16; ++qq) {
        const int j = (16 - qq) & 15;  // lane-UNIFORM x column
        const int q = (qq + n) & 15;   // lane-varying k column
        const float* xcol = xb + (size_t)j * CH;  // rows s = d*16 + j

        // kv[16]: distinct-address b128 LDS reads (conflict-free, measured 0)
        float4 kv[16];
#pragma unroll
        for (int p = 0; p < 16; ++p)
            kv[p] = *(const float4*)&ks[(p << 4) | q][chq];

        // d = (m - p) & 15: one coalesced global x row per d, indices static
#pragma unroll
        for (int d = 0; d < 16; ++d) {
            const float4 xx = *(const float4*)(xcol + (size_t)(d << 4) * CH);
#pragma unroll
            for (int p = 0; p < 16; ++p) {
                const int m = (p + d) & 15;  // compile-time
                acc[m].x = fmaf(kv[p].x, xx.x, acc[m].x);
                acc[m].y = fmaf(kv[p].y, xx.y, acc[m].y);
                acc[m].z = fmaf(kv[p].z, xx.z, acc[m].z);
                acc[m].w = fmaf(kv[p].w, xx.w, acc[m].w);
            }
        }
    }

    float* ob = out + (size_t)b * NS * CH + c0 + chq;
#pragma unroll
    for (int m = 0; m < 16; ++m)
        *(float4*)(ob + (size_t)((m << 4) + n) * CH) = acc[m];
}

// ---------------------------------------------------------------------------
extern "C" void kernel_launch(void* const* d_in, const int* in_sizes, int n_in,
                              void* d_out, int out_size, void* d_ws, size_t ws_size,
                              hipStream_t stream) {
    const float* x = (const float*)d_in[0];        // [128, 256, 768] fp32
    const float* w = (const float*)d_in[1];        // [16, 9, 768, 2] fp32
    float* out  = (float*)d_out;                   // [128, 256, 768] fp32
    float* kbuf = (float*)d_ws;                    // 256*768 fp32 = 768 KB

    gf_build_k<<<dim3(256, 3), 256, 0, stream>>>(w, kbuf);
    gf_conv<<<dim3(CH / 32, NB / 2), 256, 0, stream>>>(x, kbuf, out);
}

// Round 5
// 299.365 us; speedup vs baseline: 10.0562x; 1.4183x over previous
//
#include <hip/hip_runtime.h>

// GlobalFilter (GFNet): out = irfft2(rfft2(x)·W, ortho) == per-channel 16x16
// circular convolution with k[:,:,c] = inverse transform of W. ortho norms cancel.
//
// Lessons:
//  R1: k reads are a per-lane GATHER -> k MUST stay in LDS. x rows are
//      n-independent broadcasts/coalesced -> LDS optional for x.
//  R2: dynamic reg-array index -> scratch. Only compile-time indices.
//  R3: conditionals in hot unrolled loops -> spill. Branch-free bodies only.
//  R4 (300 us): 64 KB LDS -> 1 wave/SIMD. VALUBusy 50%.
//  R5 (281 us, conv 149): x column streamed into LDS, prefetch 1 qq ahead,
//      16 in-loop barriers. Occ 27%, VALUBusy 66%.
//  R6/R7 (3010/2757 us): __launch_bounds__(256,4) caps unified regfile at
//      128/thread < live set (acc64+kv64+addr) -> degenerate 64-VGPR spill
//      (WRITE 6-9 GB). This register tile supports AT MOST 3 waves/SIMD.
//  R8 (conv 296): x direct from global, zero barriers - but compiler kept
//      only ~1 xx load in flight (VGPR stayed 84): each d-step serialized on
//      L2 latency, VALUBusy 32%. LESSON: removing the prefetch mechanism
//      removed the latency hiding; barriers weren't the only thing R5 had.
//  R9 (this version): both properties at once - (a) x requested a full
//      compute-phase early, (b) zero in-loop barriers. Explicit 4-deep
//      register ring xq[4], d-loop fully unrolled, slot (d&3) refilled at
//      step d with row (d+4)&15; steps 12..15 naturally prefetch rows 0..3
//      of the NEXT column (jn) -> ring warm across qq, branch-free. Plain
//      global loads into named VGPRs get precise counted vmcnt from the
//      compiler (no global_load_lds->ds_read aliasing conservatism).

constexpr int PP = 16;   // patch size
constexpr int NS = 256;  // PP*PP spatial
constexpr int CH = 768;  // channels
constexpr int NB = 128;  // batch

// async global->LDS, 16B per lane. lds ptr must be wave-uniform base; HW adds
// lane*16. Source address is per-lane. (Used only for the ks gather tile.)
__device__ __forceinline__ void cp_g2s_16(const void* g, void* s) {
    __builtin_amdgcn_global_load_lds(
        (const __attribute__((address_space(1))) void*)g,
        (__attribute__((address_space(3))) void*)s, 16, 0, 0);
}

// ---------------- Kernel A: build real conv kernel k[p*16+q][c] -------------
__global__ void gf_build_k(const float* __restrict__ w, float* __restrict__ kbuf) {
    __shared__ float ct[16], st[16];
    if (threadIdx.x < 16) {
        const float ang = 6.28318530717958647692f * (float)threadIdx.x * (1.0f / 16.0f);
        ct[threadIdx.x] = cosf(ang);
        st[threadIdx.x] = sinf(ang);
    }
    __syncthreads();

    const int pq = blockIdx.x;                              // 0..255
    const int c  = blockIdx.y * blockDim.x + threadIdx.x;   // 0..767
    const int p = pq >> 4, q = pq & 15;

    float acc = 0.0f;
#pragma unroll 1
    for (int u = 0; u < 16; ++u) {
        const float* wu = w + (size_t)(u * 9) * 2 * CH + 2 * c;
#pragma unroll
        for (int v = 0; v < 9; ++v) {
            const float cv = (v == 0 || v == 8) ? 1.0f : 2.0f;
            const int t = (u * p + v * q) & 15;  // lane-uniform -> LDS broadcast
            const float wr = wu[(size_t)v * 2 * CH];
            const float wi = wu[(size_t)v * 2 * CH + 1];
            acc += cv * (wr * ct[t] - wi * st[t]);
        }
    }
    kbuf[pq * CH + c] = acc * (1.0f / 256.0f);
}

// ---------------- Kernel B: depthwise 16x16 circular conv -------------------
// block = 256 threads = 2 batches x (8 ch-groups x 16 n-cols). 32 KB LDS:
//   ks[256][32]  (per-lane gather -> LDS, staged once, read-only after)
// x streamed from global through a 4-deep register ring (load-to-use distance
// 4 d-steps = ~512 cy of FMA). One barrier total (after ks staging).
__global__ __launch_bounds__(256, 3) void gf_conv(const float* __restrict__ x,
                                                  const float* __restrict__ kbuf,
                                                  float* __restrict__ out) {
    __shared__ __align__(16) float ks[NS][32];

    const int tid  = threadIdx.x;
    const int half = tid >> 7;                 // batch half 0/1
    const int b    = (blockIdx.y << 1) | half;
    const int c0   = blockIdx.x * 32;
    const int wave = tid >> 6;                 // 0..3 (wave-uniform)

    // ---- stage k tile: 8 x global_load_lds per thread, lane-linear dest.
    {
        const int srow = tid >> 3;             // 0..31
        const int kch4 = (tid & 7) << 2;
        const float* kb = kbuf + c0;
        float* lbase = &ks[0][0] + wave * 256; // 1 KB per wave, uniform
#pragma unroll
        for (int i = 0; i < 8; ++i)
            cp_g2s_16(kb + (size_t)(i * 32 + srow) * CH + kch4, lbase + i * 1024);
    }
    __syncthreads();  // ks staged. Last barrier in the kernel.

    const int chq = (tid & 7) << 2;   // channel float4 within tile
    const int n   = (tid >> 3) & 15;  // output column 0..15
    const float* xb = x + (size_t)b * NS * CH + c0 + chq;

    float4 acc[16];
#pragma unroll
    for (int m = 0; m < 16; ++m) acc[m] = make_float4(0.f, 0.f, 0.f, 0.f);

    // ---- prime the ring: rows 0..3 of column j=0
    float4 xq[4];  // static-indexed ring (R2: all indices compile-time)
#pragma unroll
    for (int i = 0; i < 4; ++i)
        xq[i] = *(const float4*)(xb + (size_t)(i << 4) * CH);

    int j = 0, jn = 15;  // current / next x column (j(qq) = (16-qq)&15)

#pragma unroll 1
    for (int qq = 0; qq < 16; ++qq) {
        const int q = (qq + n) & 15;   // lane-varying k column
        const float* colp = xb + (size_t)j * CH;   // current column base
        const float* coln = xb + (size_t)jn * CH;  // next column base

        // kv[16]: distinct-address b128 LDS reads (conflict-free, measured 0)
        float4 kv[16];
#pragma unroll
        for (int p = 0; p < 16; ++p)
            kv[p] = *(const float4*)&ks[(p << 4) | q][chq];

        // d-loop fully unrolled: consume xq[d&3] = row(d, j); refill slot with
        // row (d+4)&15 -- of col j for d<12, of col jn for d>=12 (prefetch
        // across the qq boundary). (d<12) resolves at compile time: no branch.
#pragma unroll
        for (int d = 0; d < 16; ++d) {
            const float4 xx = xq[d & 3];
            const float* src = (d < 12) ? colp : coln;
            xq[d & 3] = *(const float4*)(src + (size_t)((((d + 4) & 15)) << 4) * CH);
#pragma unroll
            for (int p = 0; p < 16; ++p) {
                const int m = (p + d) & 15;  // compile-time
                acc[m].x = fmaf(kv[p].x, xx.x, acc[m].x);
                acc[m].y = fmaf(kv[p].y, xx.y, acc[m].y);
                acc[m].z = fmaf(kv[p].z, xx.z, acc[m].z);
                acc[m].w = fmaf(kv[p].w, xx.w, acc[m].w);
            }
        }

        j = jn;
        jn = (jn - 1) & 15;
    }

    float* ob = out + (size_t)b * NS * CH + c0 + chq;
#pragma unroll
    for (int m = 0; m < 16; ++m)
        *(float4*)(ob + (size_t)((m << 4) + n) * CH) = acc[m];
}

// ---------------------------------------------------------------------------
extern "C" void kernel_launch(void* const* d_in, const int* in_sizes, int n_in,
                              void* d_out, int out_size, void* d_ws, size_t ws_size,
                              hipStream_t stream) {
    const float* x = (const float*)d_in[0];        // [128, 256, 768] fp32
    const float* w = (const float*)d_in[1];        // [16, 9, 768, 2] fp32
    float* out  = (float*)d_out;                   // [128, 256, 768] fp32
    float* kbuf = (float*)d_ws;                    // 256*768 fp32 = 768 KB

    gf_build_k<<<dim3(256, 3), 256, 0, stream>>>(w, kbuf);
    gf_conv<<<dim3(CH / 32, NB / 2), 256, 0, stream>>>(x, kbuf, out);
}